// Round 7
// baseline (819.541 us; speedup 1.0000x reference)
//
#include <hip/hip_runtime.h>
#include <hip/hip_bf16.h>
#include <cstdint>
#include <cstddef>

#define NN 50000
#define EE 800000
#define FIN 128
#define D1 128           // HEADS*HID
#define HEADS 4
#define HID 32
#define CLS 40
#define NEG 0.2f
#define MAXDEG 64        // slot0 = self-loop + up to 63 in-edges
#define PBLK 64          // build partitions (one block each, LDS histogram)
#define PSZ 782          // ceil(NN / PBLK)
#define GEMM1B 391       // ceil(NN/128)

typedef __attribute__((ext_vector_type(8))) short short8;   // 8 bf16 (4 VGPRs)
typedef __attribute__((ext_vector_type(4))) float float4v;  // MFMA C/D

union U16 { uint4 u; short8 s; };

__device__ __forceinline__ float bf2f(unsigned short u) {
    union { unsigned int i; float f; } v; v.i = ((unsigned int)u) << 16; return v.f;
}
__device__ __forceinline__ unsigned short f2bf(float f) {
    union { unsigned int i; float f; } v; v.f = f;
    unsigned int r = v.i + 0x7fffu + ((v.i >> 16) & 1u);
    return (unsigned short)(r >> 16);
}

// ---------- fused: LDS-histogram adjacency build  ∥  MFMA GEMM1+att1 ----------
// Build: 64 blocks, one per 782-node dst range. Each scans ALL edges (int4,
// redundant scan is L2-served and issue-cheap) and counts into an LDS histogram
// (ds_add_rtn, ~0 cost) instead of 800K fabric atomic RMWs (the old ~42us floor).
// Global side effects: fire-and-forget 2B scatter stores + coalesced cnt writeback.
// Self-loop is deterministic slot 0, so no cnt memset dispatch is needed at all.
union BSM {
    struct { uint4 Wl[2048]; float sas[128]; float sad[128]; } g;   // 33792 B (gemm path)
    int hist[PSZ];                                                  // 3128 B (build path)
};

__global__ __launch_bounds__(256, 4) void bg_k(const int* __restrict__ eidx,
                                               int* __restrict__ cnt,
                                               unsigned short* __restrict__ ssrcp,
                                               const float* __restrict__ X,
                                               const float* __restrict__ W,
                                               const float* __restrict__ as1,
                                               const float* __restrict__ ad1,
                                               unsigned int* __restrict__ H1b,
                                               float* __restrict__ ALS1,
                                               float* __restrict__ ALD1) {
    __shared__ BSM sm;
    int t = threadIdx.x;

    if (blockIdx.x < PBLK) {
        // ---- build path ----
        int lo = blockIdx.x * PSZ;
        int hi = min(lo + PSZ, NN);
        int n = hi - lo;
        for (int i = t; i < n; i += 256) {
            sm.hist[i] = 1;                                        // slot 0 = self
            ssrcp[(size_t)(lo + i) * MAXDEG] = (unsigned short)(lo + i);
        }
        __syncthreads();
        const int4* dst4 = (const int4*)(eidx + EE);
        for (int i4 = t; i4 < EE / 4; i4 += 256) {
            int4 d = dst4[i4];
            int base = i4 * 4;
            if (d.x >= lo && d.x < hi) {
                int s = atomicAdd(&sm.hist[d.x - lo], 1);
                if (s < MAXDEG) ssrcp[(size_t)d.x * MAXDEG + s] = (unsigned short)eidx[base];
            }
            if (d.y >= lo && d.y < hi) {
                int s = atomicAdd(&sm.hist[d.y - lo], 1);
                if (s < MAXDEG) ssrcp[(size_t)d.y * MAXDEG + s] = (unsigned short)eidx[base + 1];
            }
            if (d.z >= lo && d.z < hi) {
                int s = atomicAdd(&sm.hist[d.z - lo], 1);
                if (s < MAXDEG) ssrcp[(size_t)d.z * MAXDEG + s] = (unsigned short)eidx[base + 2];
            }
            if (d.w >= lo && d.w < hi) {
                int s = atomicAdd(&sm.hist[d.w - lo], 1);
                if (s < MAXDEG) ssrcp[(size_t)d.w * MAXDEG + s] = (unsigned short)eidx[base + 3];
            }
        }
        __syncthreads();
        for (int i = t; i < n; i += 256) cnt[lo + i] = sm.hist[i];
        return;
    }

    // ---- gemm1 path ----
    int bI = blockIdx.x - PBLK;
    if (t < 128) { sm.g.sas[t] = as1[t]; sm.g.sad[t] = ad1[t]; }
    for (int g = t; g < 2048; g += 256) {
        int ct = g >> 8, rem = g & 255, kc = rem >> 6, l = rem & 63;
        int c = ct * 16 + (l & 15);
        int k0 = kc * 32 + (l >> 4) * 8;
        U16 u;
#pragma unroll
        for (int j = 0; j < 8; j++) u.s[j] = (short)f2bf(W[(k0 + j) * D1 + c]);
        sm.g.Wl[g] = u.u;
    }
    __syncthreads();

    int wid = t >> 6, lane = t & 63, quad = lane >> 4, lrow = lane & 15;
    int wrow0 = bI * 128 + wid * 32;

    short8 afr[2][4];
#pragma unroll
    for (int rt = 0; rt < 2; rt++) {
        int r = wrow0 + rt * 16 + lrow;
#pragma unroll
        for (int kc = 0; kc < 4; kc++) {
            short8 a = {0, 0, 0, 0, 0, 0, 0, 0};
            if (r < NN) {
                const float* xp = X + (size_t)r * FIN + kc * 32 + quad * 8;
                float4 x0 = *(const float4*)xp;
                float4 x1 = *(const float4*)(xp + 4);
                a[0] = (short)f2bf(x0.x); a[1] = (short)f2bf(x0.y);
                a[2] = (short)f2bf(x0.z); a[3] = (short)f2bf(x0.w);
                a[4] = (short)f2bf(x1.x); a[5] = (short)f2bf(x1.y);
                a[6] = (short)f2bf(x1.z); a[7] = (short)f2bf(x1.w);
            }
            afr[rt][kc] = a;
        }
    }

    float4v acc[2][4];

    for (int cp = 0; cp < 2; ++cp) {
#pragma unroll
        for (int rt = 0; rt < 2; rt++)
#pragma unroll
            for (int c4 = 0; c4 < 4; c4++) acc[rt][c4] = (float4v)(0.f);

#pragma unroll
        for (int c4 = 0; c4 < 4; c4++) {
#pragma unroll
            for (int kc = 0; kc < 4; kc++) {
                U16 b; b.u = sm.g.Wl[((cp * 4 + c4) * 4 + kc) * 64 + lane];
                acc[0][c4] = __builtin_amdgcn_mfma_f32_16x16x32_bf16(afr[0][kc], b.s, acc[0][c4], 0, 0, 0);
                acc[1][c4] = __builtin_amdgcn_mfma_f32_16x16x32_bf16(afr[1][kc], b.s, acc[1][c4], 0, 0, 0);
            }
        }

        // fused att1 for heads 2*cp and 2*cp+1
#pragma unroll
        for (int rt = 0; rt < 2; rt++) {
#pragma unroll
            for (int reg = 0; reg < 4; reg++) {
                float ps[2] = {0.f, 0.f};
                float pd[2] = {0.f, 0.f};
#pragma unroll
                for (int c4 = 0; c4 < 4; c4++) {
                    float v = acc[rt][c4][reg];
                    int ct = cp * 4 + c4;
                    ps[c4 >> 1] += v * sm.g.sas[ct * 16 + lrow];
                    pd[c4 >> 1] += v * sm.g.sad[ct * 16 + lrow];
                }
#pragma unroll
                for (int o = 1; o < 16; o <<= 1) {
#pragma unroll
                    for (int h = 0; h < 2; h++) {
                        ps[h] += __shfl_xor(ps[h], o);
                        pd[h] += __shfl_xor(pd[h], o);
                    }
                }
                int r = wrow0 + rt * 16 + quad * 4 + reg;
                if (lrow == 0 && r < NN) {
                    *(float2*)&ALS1[(size_t)r * 4 + cp * 2] = make_float2(ps[0], ps[1]);
                    *(float2*)&ALD1[(size_t)r * 4 + cp * 2] = make_float2(pd[0], pd[1]);
                }
            }
        }

        // C/D pack for columns of this pass
#pragma unroll
        for (int rt = 0; rt < 2; rt++)
#pragma unroll
            for (int c4 = 0; c4 < 4; c4++)
#pragma unroll
                for (int reg = 0; reg < 4; reg++) {
                    float v = acc[rt][c4][reg];
                    float o = __shfl_xor(v, 1);
                    int r = wrow0 + rt * 16 + quad * 4 + reg;
                    if (((lane & 1) == 0) && r < NN) {
                        unsigned int u = (unsigned int)f2bf(v) | ((unsigned int)f2bf(o) << 16);
                        H1b[(size_t)r * 64 + (cp * 4 + c4) * 8 + (lrow >> 1)] = u;
                    }
                }
    }
}

// ---------- gather layer1: wave-per-node, 1-ahead software pipeline ----------
__global__ __launch_bounds__(256) void gather1_k(const int* __restrict__ cnt,
                                                 const unsigned short* __restrict__ ssrcp,
                                                 const uint4* __restrict__ H1b4,
                                                 const float4* __restrict__ ALS,
                                                 const float4* __restrict__ ALD,
                                                 const float* __restrict__ b1,
                                                 uint4* __restrict__ OUT1b4) {
    __shared__ float wlds[4][MAXDEG][4];
    __shared__ int sidlds[4][MAXDEG];
    int wid = threadIdx.x >> 6, lane = threadIdx.x & 63;
    int v = blockIdx.x * 4 + wid;           // grid*4 == NN exactly
    int deg = min(cnt[v], MAXDEG);
    float4 ad = ALD[v];
    float w0 = 0.f, w1 = 0.f, w2 = 0.f, w3 = 0.f;
    if (lane < deg) {
        int s = (int)ssrcp[(size_t)v * MAXDEG + lane];
        sidlds[wid][lane] = s;
        float4 as = ALS[s];
        float l0 = as.x + ad.x; l0 = l0 > 0.f ? l0 : NEG * l0;
        float l1 = as.y + ad.y; l1 = l1 > 0.f ? l1 : NEG * l1;
        float l2 = as.z + ad.z; l2 = l2 > 0.f ? l2 : NEG * l2;
        float l3 = as.w + ad.w; l3 = l3 > 0.f ? l3 : NEG * l3;
        w0 = __expf(l0); w1 = __expf(l1); w2 = __expf(l2); w3 = __expf(l3);
        wlds[wid][lane][0] = w0; wlds[wid][lane][1] = w1;
        wlds[wid][lane][2] = w2; wlds[wid][lane][3] = w3;
    }
    float d0 = w0, d1 = w1, d2 = w2, d3 = w3;
#pragma unroll
    for (int o = 1; o < 64; o <<= 1) {
        d0 += __shfl_xor(d0, o); d1 += __shfl_xor(d1, o);
        d2 += __shfl_xor(d2, o); d3 += __shfl_xor(d3, o);
    }
    __syncthreads();
    int g = lane >> 4, l = lane & 15, head = l >> 2;
    float a0=0.f,a1=0.f,a2=0.f,a3=0.f,a4=0.f,a5=0.f,a6=0.f,a7=0.f;
    {
        int j = g;
        bool valid = j < deg;
        float wj = 0.f; uint4 q = {};
        if (valid) {
            wj = wlds[wid][j][head];
            q = H1b4[(size_t)sidlds[wid][j] * 16 + l];
        }
        while (valid) {
            int jn = j + 4;
            bool vn = jn < deg;
            float wn = 0.f; uint4 qn = {};
            if (vn) {
                wn = wlds[wid][jn][head];
                qn = H1b4[(size_t)sidlds[wid][jn] * 16 + l];
            }
            a0 += wj * bf2f((unsigned short)(q.x & 0xffffu));
            a1 += wj * bf2f((unsigned short)(q.x >> 16));
            a2 += wj * bf2f((unsigned short)(q.y & 0xffffu));
            a3 += wj * bf2f((unsigned short)(q.y >> 16));
            a4 += wj * bf2f((unsigned short)(q.z & 0xffffu));
            a5 += wj * bf2f((unsigned short)(q.z >> 16));
            a6 += wj * bf2f((unsigned short)(q.w & 0xffffu));
            a7 += wj * bf2f((unsigned short)(q.w >> 16));
            j = jn; valid = vn; wj = wn; q = qn;
        }
    }
#pragma unroll
    for (int o = 16; o < 64; o <<= 1) {
        a0 += __shfl_xor(a0, o); a1 += __shfl_xor(a1, o);
        a2 += __shfl_xor(a2, o); a3 += __shfl_xor(a3, o);
        a4 += __shfl_xor(a4, o); a5 += __shfl_xor(a5, o);
        a6 += __shfl_xor(a6, o); a7 += __shfl_xor(a7, o);
    }
    if (lane < 16) {
        float den = (head == 0) ? d0 : (head == 1) ? d1 : (head == 2) ? d2 : d3;
        den += 1e-16f;
        float4 bA = *(const float4*)&b1[8 * l];
        float4 bB = *(const float4*)&b1[8 * l + 4];
        float o0 = fmaxf(a0 / den + bA.x, 0.f);
        float o1 = fmaxf(a1 / den + bA.y, 0.f);
        float o2 = fmaxf(a2 / den + bA.z, 0.f);
        float o3 = fmaxf(a3 / den + bA.w, 0.f);
        float o4 = fmaxf(a4 / den + bB.x, 0.f);
        float o5 = fmaxf(a5 / den + bB.y, 0.f);
        float o6 = fmaxf(a6 / den + bB.z, 0.f);
        float o7 = fmaxf(a7 / den + bB.w, 0.f);
        uint4 u;
        u.x = (unsigned int)f2bf(o0) | ((unsigned int)f2bf(o1) << 16);
        u.y = (unsigned int)f2bf(o2) | ((unsigned int)f2bf(o3) << 16);
        u.z = (unsigned int)f2bf(o4) | ((unsigned int)f2bf(o5) << 16);
        u.w = (unsigned int)f2bf(o6) | ((unsigned int)f2bf(o7) << 16);
        OUT1b4[(size_t)v * 16 + l] = u;
    }
}

// ---------- GEMM2 via MFMA + fused att2 logits ----------
__global__ __launch_bounds__(256) void gemm2_k(const unsigned int* __restrict__ OUT1b,
                                               const float* __restrict__ W2,
                                               const float* __restrict__ as2,
                                               const float* __restrict__ ad2,
                                               unsigned int* __restrict__ H2b,
                                               float* __restrict__ ALS2,
                                               float* __restrict__ ALD2) {
    __shared__ uint4 Wl[768];   // 12 KiB: 3 ct x 4 kc x 64 lanes
    __shared__ float sas[48], sad[48];
    int t = threadIdx.x;
    if (t < 48) {
        sas[t] = (t < CLS) ? as2[t] : 0.f;
        sad[t] = (t < CLS) ? ad2[t] : 0.f;
    }
    for (int g = t; g < 768; g += 256) {
        int ct = g >> 8, rem = g & 255, kc = rem >> 6, l = rem & 63;
        int c = ct * 16 + (l & 15);
        int k0 = kc * 32 + (l >> 4) * 8;
        U16 u;
#pragma unroll
        for (int j = 0; j < 8; j++)
            u.s[j] = (c < CLS) ? (short)f2bf(W2[(k0 + j) * CLS + c]) : (short)0;
        Wl[g] = u.u;
    }
    __syncthreads();

    int wid = t >> 6, lane = t & 63, quad = lane >> 4, lrow = lane & 15;
    int wrow0 = blockIdx.x * 128 + wid * 32;

    U16 afr[2][4];
#pragma unroll
    for (int rt = 0; rt < 2; rt++) {
        int r = wrow0 + rt * 16 + lrow;
#pragma unroll
        for (int kc = 0; kc < 4; kc++) {
            if (r < NN)
                afr[rt][kc].u = ((const uint4*)OUT1b)[(size_t)r * 16 + kc * 4 + quad];
            else
                afr[rt][kc].u = make_uint4(0, 0, 0, 0);
        }
    }

    float4v acc[2][3];
#pragma unroll
    for (int rt = 0; rt < 2; rt++)
#pragma unroll
        for (int ct = 0; ct < 3; ct++) acc[rt][ct] = (float4v)(0.f);

#pragma unroll
    for (int ct = 0; ct < 3; ct++) {
#pragma unroll
        for (int kc = 0; kc < 4; kc++) {
            U16 b; b.u = Wl[(ct * 4 + kc) * 64 + lane];
            acc[0][ct] = __builtin_amdgcn_mfma_f32_16x16x32_bf16(afr[0][kc].s, b.s, acc[0][ct], 0, 0, 0);
            acc[1][ct] = __builtin_amdgcn_mfma_f32_16x16x32_bf16(afr[1][kc].s, b.s, acc[1][ct], 0, 0, 0);
        }
    }

    // fused att2
#pragma unroll
    for (int rt = 0; rt < 2; rt++) {
#pragma unroll
        for (int reg = 0; reg < 4; reg++) {
            float ps = 0.f, pd = 0.f;
#pragma unroll
            for (int ct = 0; ct < 3; ct++) {
                float v = acc[rt][ct][reg];
                ps += v * sas[ct * 16 + lrow];
                pd += v * sad[ct * 16 + lrow];
            }
#pragma unroll
            for (int o = 1; o < 16; o <<= 1) {
                ps += __shfl_xor(ps, o);
                pd += __shfl_xor(pd, o);
            }
            int r = wrow0 + rt * 16 + quad * 4 + reg;
            if (lrow == 0 && r < NN) {
                ALS2[r] = ps;
                ALD2[r] = pd;
            }
        }
    }

#pragma unroll
    for (int rt = 0; rt < 2; rt++)
#pragma unroll
        for (int ct = 0; ct < 3; ct++)
#pragma unroll
            for (int reg = 0; reg < 4; reg++) {
                float v = acc[rt][ct][reg];
                float o = __shfl_xor(v, 1);
                int r = wrow0 + rt * 16 + quad * 4 + reg;
                int c = ct * 16 + lrow;
                if (((lane & 1) == 0) && c < CLS && r < NN) {
                    unsigned int u = (unsigned int)f2bf(v) | ((unsigned int)f2bf(o) << 16);
                    H2b[(size_t)r * 20 + (c >> 1)] = u;
                }
            }
}

// ---------- gather layer2: 4 nodes/block, 3x20 lanes, 1-ahead pipeline ----------
__global__ __launch_bounds__(256) void gather2_k(const int* __restrict__ cnt,
                                                 const unsigned short* __restrict__ ssrcp,
                                                 const unsigned int* __restrict__ H2b,
                                                 const float* __restrict__ ALS,
                                                 const float* __restrict__ ALD,
                                                 const float* __restrict__ b2,
                                                 float* __restrict__ out) {
    int wid = threadIdx.x >> 6, t = threadIdx.x & 63;
    int v = blockIdx.x * 4 + wid;          // grid*4 == NN exactly
    int deg = min(cnt[v], MAXDEG);
    __shared__ float w[4][MAXDEG];
    __shared__ int sid[4][MAXDEG];
    __shared__ float part[4][3][CLS];
    float den = 0.f;
    float adv = ALD[v];
    if (t < deg) {
        int s = (int)ssrcp[(size_t)v * MAXDEG + t];
        sid[wid][t] = s;
        float l = ALS[s] + adv; l = l > 0.f ? l : NEG * l;
        float e = __expf(l);
        w[wid][t] = e; den = e;
    }
    __syncthreads();
    int g = t / 20, c = t % 20;   // 3 edge-groups x 20 lanes (t<60); c = uint idx (2 ch)
    if (t < 60) {
        float ax = 0.f, ay = 0.f;
        int j = g;
        bool valid = j < deg;
        float wj = 0.f; unsigned int u = 0u;
        if (valid) { wj = w[wid][j]; u = H2b[(size_t)sid[wid][j] * 20 + c]; }
        while (valid) {
            int jn = j + 3;
            bool vn = jn < deg;
            float wn = 0.f; unsigned int un = 0u;
            if (vn) { wn = w[wid][jn]; un = H2b[(size_t)sid[wid][jn] * 20 + c]; }
            ax += wj * bf2f((unsigned short)(u & 0xffffu));
            ay += wj * bf2f((unsigned short)(u >> 16));
            j = jn; valid = vn; wj = wn; u = un;
        }
        part[wid][g][2 * c] = ax;
        part[wid][g][2 * c + 1] = ay;
    }
#pragma unroll
    for (int o = 32; o > 0; o >>= 1) den += __shfl_xor(den, o);
    __syncthreads();
    float z = (t < CLS) ? (part[wid][0][t] + part[wid][1][t] + part[wid][2][t]) / (den + 1e-16f) + b2[t]
                        : -1e30f;
    float mx = z;
#pragma unroll
    for (int o = 32; o > 0; o >>= 1) mx = fmaxf(mx, __shfl_xor(mx, o));
    float ex = (t < CLS) ? __expf(z - mx) : 0.f;
    float se = ex;
#pragma unroll
    for (int o = 32; o > 0; o >>= 1) se += __shfl_xor(se, o);
    if (t < CLS) out[(size_t)v * CLS + t] = z - mx - __logf(se);
}

extern "C" void kernel_launch(void* const* d_in, const int* in_sizes, int n_in,
                              void* d_out, int out_size, void* d_ws, size_t ws_size,
                              hipStream_t stream) {
    const float* x   = (const float*)d_in[0];
    const int*   eix = (const int*)d_in[1];
    const float* W1  = (const float*)d_in[2];
    const float* as1 = (const float*)d_in[3];
    const float* ad1 = (const float*)d_in[4];
    const float* b1  = (const float*)d_in[5];
    const float* W2  = (const float*)d_in[6];
    const float* as2 = (const float*)d_in[7];
    const float* ad2 = (const float*)d_in[8];
    const float* b2  = (const float*)d_in[9];
    float* out = (float*)d_out;

    char* p = (char*)d_ws;
    auto carve = [&](size_t bytes) -> void* {
        void* r = (void*)p;
        p += (bytes + 255) & ~(size_t)255;
        return r;
    };
    unsigned int* H1b   = (unsigned int*)carve((size_t)NN * 64 * 4);  // bf16x2 packed
    unsigned int* OUT1b = (unsigned int*)carve((size_t)NN * 64 * 4);  // bf16x2 packed
    unsigned int* H2b   = (unsigned int*)carve((size_t)NN * 20 * 4);  // bf16x2 packed (4 MB)
    float* ALS1 = (float*)carve((size_t)NN * 4 * 4);
    float* ALD1 = (float*)carve((size_t)NN * 4 * 4);
    float* ALS2 = (float*)carve((size_t)NN * 4);
    float* ALD2 = (float*)carve((size_t)NN * 4);
    int* cnt    = (int*)carve((size_t)NN * 4);
    unsigned short* ssrcp = (unsigned short*)carve((size_t)NN * MAXDEG * 2);

    // no cnt memset: build blocks fully overwrite cnt[0..NN) every run

    bg_k<<<PBLK + GEMM1B, 256, 0, stream>>>(eix, cnt, ssrcp, x, W1, as1, ad1,
                                            H1b, ALS1, ALD1);
    gather1_k<<<NN / 4, 256, 0, stream>>>(cnt, ssrcp, (const uint4*)H1b,
                                          (const float4*)ALS1, (const float4*)ALD1,
                                          b1, (uint4*)OUT1b);
    gemm2_k<<<(NN + 127) / 128, 256, 0, stream>>>(OUT1b, W2, as2, ad2, H2b, ALS2, ALD2);
    gather2_k<<<NN / 4, 256, 0, stream>>>(cnt, ssrcp, H2b, ALS2, ALD2, b2, out);
}

// Round 8
// 206.136 us; speedup vs baseline: 3.9757x; 3.9757x over previous
//
#include <hip/hip_runtime.h>
#include <hip/hip_bf16.h>
#include <cstdint>
#include <cstddef>

#define NN 50000
#define EE 800000
#define FIN 128
#define D1 128           // HEADS*HID
#define HEADS 4
#define HID 32
#define CLS 40
#define NEG 0.2f
#define MAXDEG 64        // slot0 = self-loop + up to 63 in-edges; P(deg>64) ~ 1e-20
#define P2 128           // dst partitions (radix build)
#define PSZ2 391         // ceil(NN / P2)
#define CAP 8192         // pairs per partition segment (mean 6250, +24 sigma)
#define ABLK 400         // bucket_k blocks
#define ASLICE 500       // int4 edges per bucket_k block (400*500*4 == EE)
#define GEMM1B 391       // ceil(NN/128)

typedef __attribute__((ext_vector_type(8))) short short8;   // 8 bf16 (4 VGPRs)
typedef __attribute__((ext_vector_type(4))) float float4v;  // MFMA C/D

union U16 { uint4 u; short8 s; };

__device__ __forceinline__ float bf2f(unsigned short u) {
    union { unsigned int i; float f; } v; v.i = ((unsigned int)u) << 16; return v.f;
}
__device__ __forceinline__ unsigned short f2bf(float f) {
    union { unsigned int i; float f; } v; v.f = f;
    unsigned int r = v.i + 0x7fffu + ((v.i >> 16) & 1u);
    return (unsigned short)(r >> 16);
}

// ---------- phase A: bucket edges by dst partition, compacted segments ----------
// 400 blocks x 2000 edges. Global RMWs: one per (block,partition) = 51K total
// (vs 850K per-edge RMWs = the old ~42us fabric floor). Pair scatter stores are
// fire-and-forget. Slot assignment deferred to phase B (LDS histogram there).
__global__ __launch_bounds__(256) void bucket_k(const int* __restrict__ eidx,
                                                unsigned int* __restrict__ seg,
                                                int* __restrict__ seg_cnt) {
    __shared__ int hist[P2], base_s[P2], run[P2];
    int t = threadIdx.x;
    if (t < P2) { hist[t] = 0; run[t] = 0; }
    __syncthreads();
    const int4* dst4 = (const int4*)(eidx + EE);
    const int4* src4 = (const int4*)eidx;
    int i0 = blockIdx.x * ASLICE;
    // pass 1: count per partition
    for (int i = i0 + t; i < i0 + ASLICE; i += 256) {
        int4 d = dst4[i];
        atomicAdd(&hist[d.x / PSZ2], 1);
        atomicAdd(&hist[d.y / PSZ2], 1);
        atomicAdd(&hist[d.z / PSZ2], 1);
        atomicAdd(&hist[d.w / PSZ2], 1);
    }
    __syncthreads();
    // reserve contiguous ranges (one fabric RMW per nonzero partition)
    if (t < P2) base_s[t] = (hist[t] > 0) ? atomicAdd(&seg_cnt[t], hist[t]) : 0;
    __syncthreads();
    // pass 2: place pairs
    for (int i = i0 + t; i < i0 + ASLICE; i += 256) {
        int4 d = dst4[i];
        int4 s = src4[i];
        int p, off, idx;
        p = d.x / PSZ2; off = atomicAdd(&run[p], 1); idx = base_s[p] + off;
        if (idx < CAP) seg[(size_t)p * CAP + idx] = ((unsigned)s.x << 16) | (unsigned)(d.x - p * PSZ2);
        p = d.y / PSZ2; off = atomicAdd(&run[p], 1); idx = base_s[p] + off;
        if (idx < CAP) seg[(size_t)p * CAP + idx] = ((unsigned)s.y << 16) | (unsigned)(d.y - p * PSZ2);
        p = d.z / PSZ2; off = atomicAdd(&run[p], 1); idx = base_s[p] + off;
        if (idx < CAP) seg[(size_t)p * CAP + idx] = ((unsigned)s.z << 16) | (unsigned)(d.z - p * PSZ2);
        p = d.w / PSZ2; off = atomicAdd(&run[p], 1); idx = base_s[p] + off;
        if (idx < CAP) seg[(size_t)p * CAP + idx] = ((unsigned)s.w << 16) | (unsigned)(d.w - p * PSZ2);
    }
}

// ---------- fused: phase B slot assignment (128 blocks)  ∥  MFMA GEMM1+att1 ----------
union BSM {
    struct { uint4 Wl[2048]; float sas[128]; float sad[128]; } g;   // 33792 B (gemm path)
    int hist[PSZ2];                                                  // 1564 B (build path)
};

__global__ __launch_bounds__(256, 4) void bg_k(const unsigned int* __restrict__ seg,
                                               const int* __restrict__ seg_cnt,
                                               int* __restrict__ cnt,
                                               unsigned short* __restrict__ ssrcp,
                                               const float* __restrict__ X,
                                               const float* __restrict__ W,
                                               const float* __restrict__ as1,
                                               const float* __restrict__ ad1,
                                               unsigned int* __restrict__ H1b,
                                               float* __restrict__ ALS1,
                                               float* __restrict__ ALD1) {
    __shared__ BSM sm;
    int t = threadIdx.x;

    if (blockIdx.x < P2) {
        // ---- build path: contiguous pair segment -> LDS histogram slots ----
        int p = blockIdx.x;
        int lo = p * PSZ2;
        int psz = min(PSZ2, NN - lo);
        for (int i = t; i < psz; i += 256) {
            sm.hist[i] = 1;                                          // slot 0 = self
            ssrcp[(size_t)(lo + i) * MAXDEG] = (unsigned short)(lo + i);
        }
        __syncthreads();
        int m = min(seg_cnt[p], CAP);
        const unsigned int* sp = seg + (size_t)p * CAP;
        for (int i = t; i < m; i += 256) {
            unsigned int pr = sp[i];
            int dl  = (int)(pr & 0xffffu);
            int src = (int)(pr >> 16);
            int slot = atomicAdd(&sm.hist[dl], 1);
            if (slot < MAXDEG) ssrcp[(size_t)(lo + dl) * MAXDEG + slot] = (unsigned short)src;
        }
        __syncthreads();
        for (int i = t; i < psz; i += 256) cnt[lo + i] = sm.hist[i];
        return;
    }

    // ---- gemm1 path ----
    int bI = blockIdx.x - P2;
    if (t < 128) { sm.g.sas[t] = as1[t]; sm.g.sad[t] = ad1[t]; }
    for (int g = t; g < 2048; g += 256) {
        int ct = g >> 8, rem = g & 255, kc = rem >> 6, l = rem & 63;
        int c = ct * 16 + (l & 15);
        int k0 = kc * 32 + (l >> 4) * 8;
        U16 u;
#pragma unroll
        for (int j = 0; j < 8; j++) u.s[j] = (short)f2bf(W[(k0 + j) * D1 + c]);
        sm.g.Wl[g] = u.u;
    }
    __syncthreads();

    int wid = t >> 6, lane = t & 63, quad = lane >> 4, lrow = lane & 15;
    int wrow0 = bI * 128 + wid * 32;

    short8 afr[2][4];
#pragma unroll
    for (int rt = 0; rt < 2; rt++) {
        int r = wrow0 + rt * 16 + lrow;
#pragma unroll
        for (int kc = 0; kc < 4; kc++) {
            short8 a = {0, 0, 0, 0, 0, 0, 0, 0};
            if (r < NN) {
                const float* xp = X + (size_t)r * FIN + kc * 32 + quad * 8;
                float4 x0 = *(const float4*)xp;
                float4 x1 = *(const float4*)(xp + 4);
                a[0] = (short)f2bf(x0.x); a[1] = (short)f2bf(x0.y);
                a[2] = (short)f2bf(x0.z); a[3] = (short)f2bf(x0.w);
                a[4] = (short)f2bf(x1.x); a[5] = (short)f2bf(x1.y);
                a[6] = (short)f2bf(x1.z); a[7] = (short)f2bf(x1.w);
            }
            afr[rt][kc] = a;
        }
    }

    float4v acc[2][4];

    for (int cp = 0; cp < 2; ++cp) {
#pragma unroll
        for (int rt = 0; rt < 2; rt++)
#pragma unroll
            for (int c4 = 0; c4 < 4; c4++) acc[rt][c4] = (float4v)(0.f);

#pragma unroll
        for (int c4 = 0; c4 < 4; c4++) {
#pragma unroll
            for (int kc = 0; kc < 4; kc++) {
                U16 b; b.u = sm.g.Wl[((cp * 4 + c4) * 4 + kc) * 64 + lane];
                acc[0][c4] = __builtin_amdgcn_mfma_f32_16x16x32_bf16(afr[0][kc], b.s, acc[0][c4], 0, 0, 0);
                acc[1][c4] = __builtin_amdgcn_mfma_f32_16x16x32_bf16(afr[1][kc], b.s, acc[1][c4], 0, 0, 0);
            }
        }

        // fused att1 for heads 2*cp and 2*cp+1
#pragma unroll
        for (int rt = 0; rt < 2; rt++) {
#pragma unroll
            for (int reg = 0; reg < 4; reg++) {
                float ps[2] = {0.f, 0.f};
                float pd[2] = {0.f, 0.f};
#pragma unroll
                for (int c4 = 0; c4 < 4; c4++) {
                    float v = acc[rt][c4][reg];
                    int ct = cp * 4 + c4;
                    ps[c4 >> 1] += v * sm.g.sas[ct * 16 + lrow];
                    pd[c4 >> 1] += v * sm.g.sad[ct * 16 + lrow];
                }
#pragma unroll
                for (int o = 1; o < 16; o <<= 1) {
#pragma unroll
                    for (int h = 0; h < 2; h++) {
                        ps[h] += __shfl_xor(ps[h], o);
                        pd[h] += __shfl_xor(pd[h], o);
                    }
                }
                int r = wrow0 + rt * 16 + quad * 4 + reg;
                if (lrow == 0 && r < NN) {
                    *(float2*)&ALS1[(size_t)r * 4 + cp * 2] = make_float2(ps[0], ps[1]);
                    *(float2*)&ALD1[(size_t)r * 4 + cp * 2] = make_float2(pd[0], pd[1]);
                }
            }
        }

        // C/D pack for columns of this pass
#pragma unroll
        for (int rt = 0; rt < 2; rt++)
#pragma unroll
            for (int c4 = 0; c4 < 4; c4++)
#pragma unroll
                for (int reg = 0; reg < 4; reg++) {
                    float v = acc[rt][c4][reg];
                    float o = __shfl_xor(v, 1);
                    int r = wrow0 + rt * 16 + quad * 4 + reg;
                    if (((lane & 1) == 0) && r < NN) {
                        unsigned int u = (unsigned int)f2bf(v) | ((unsigned int)f2bf(o) << 16);
                        H1b[(size_t)r * 64 + (cp * 4 + c4) * 8 + (lrow >> 1)] = u;
                    }
                }
    }
}

// ---------- gather layer1: wave-per-node, 1-ahead software pipeline ----------
__global__ __launch_bounds__(256) void gather1_k(const int* __restrict__ cnt,
                                                 const unsigned short* __restrict__ ssrcp,
                                                 const uint4* __restrict__ H1b4,
                                                 const float4* __restrict__ ALS,
                                                 const float4* __restrict__ ALD,
                                                 const float* __restrict__ b1,
                                                 uint4* __restrict__ OUT1b4) {
    __shared__ float wlds[4][MAXDEG][4];
    __shared__ int sidlds[4][MAXDEG];
    int wid = threadIdx.x >> 6, lane = threadIdx.x & 63;
    int v = blockIdx.x * 4 + wid;           // grid*4 == NN exactly
    int deg = min(cnt[v], MAXDEG);
    float4 ad = ALD[v];
    float w0 = 0.f, w1 = 0.f, w2 = 0.f, w3 = 0.f;
    if (lane < deg) {
        int s = (int)ssrcp[(size_t)v * MAXDEG + lane];
        sidlds[wid][lane] = s;
        float4 as = ALS[s];
        float l0 = as.x + ad.x; l0 = l0 > 0.f ? l0 : NEG * l0;
        float l1 = as.y + ad.y; l1 = l1 > 0.f ? l1 : NEG * l1;
        float l2 = as.z + ad.z; l2 = l2 > 0.f ? l2 : NEG * l2;
        float l3 = as.w + ad.w; l3 = l3 > 0.f ? l3 : NEG * l3;
        w0 = __expf(l0); w1 = __expf(l1); w2 = __expf(l2); w3 = __expf(l3);
        wlds[wid][lane][0] = w0; wlds[wid][lane][1] = w1;
        wlds[wid][lane][2] = w2; wlds[wid][lane][3] = w3;
    }
    float d0 = w0, d1 = w1, d2 = w2, d3 = w3;
#pragma unroll
    for (int o = 1; o < 64; o <<= 1) {
        d0 += __shfl_xor(d0, o); d1 += __shfl_xor(d1, o);
        d2 += __shfl_xor(d2, o); d3 += __shfl_xor(d3, o);
    }
    __syncthreads();
    int g = lane >> 4, l = lane & 15, head = l >> 2;
    float a0=0.f,a1=0.f,a2=0.f,a3=0.f,a4=0.f,a5=0.f,a6=0.f,a7=0.f;
    {
        int j = g;
        bool valid = j < deg;
        float wj = 0.f; uint4 q = {};
        if (valid) {
            wj = wlds[wid][j][head];
            q = H1b4[(size_t)sidlds[wid][j] * 16 + l];
        }
        while (valid) {
            int jn = j + 4;
            bool vn = jn < deg;
            float wn = 0.f; uint4 qn = {};
            if (vn) {
                wn = wlds[wid][jn][head];
                qn = H1b4[(size_t)sidlds[wid][jn] * 16 + l];
            }
            a0 += wj * bf2f((unsigned short)(q.x & 0xffffu));
            a1 += wj * bf2f((unsigned short)(q.x >> 16));
            a2 += wj * bf2f((unsigned short)(q.y & 0xffffu));
            a3 += wj * bf2f((unsigned short)(q.y >> 16));
            a4 += wj * bf2f((unsigned short)(q.z & 0xffffu));
            a5 += wj * bf2f((unsigned short)(q.z >> 16));
            a6 += wj * bf2f((unsigned short)(q.w & 0xffffu));
            a7 += wj * bf2f((unsigned short)(q.w >> 16));
            j = jn; valid = vn; wj = wn; q = qn;
        }
    }
#pragma unroll
    for (int o = 16; o < 64; o <<= 1) {
        a0 += __shfl_xor(a0, o); a1 += __shfl_xor(a1, o);
        a2 += __shfl_xor(a2, o); a3 += __shfl_xor(a3, o);
        a4 += __shfl_xor(a4, o); a5 += __shfl_xor(a5, o);
        a6 += __shfl_xor(a6, o); a7 += __shfl_xor(a7, o);
    }
    if (lane < 16) {
        float den = (head == 0) ? d0 : (head == 1) ? d1 : (head == 2) ? d2 : d3;
        den += 1e-16f;
        float4 bA = *(const float4*)&b1[8 * l];
        float4 bB = *(const float4*)&b1[8 * l + 4];
        float o0 = fmaxf(a0 / den + bA.x, 0.f);
        float o1 = fmaxf(a1 / den + bA.y, 0.f);
        float o2 = fmaxf(a2 / den + bA.z, 0.f);
        float o3 = fmaxf(a3 / den + bA.w, 0.f);
        float o4 = fmaxf(a4 / den + bB.x, 0.f);
        float o5 = fmaxf(a5 / den + bB.y, 0.f);
        float o6 = fmaxf(a6 / den + bB.z, 0.f);
        float o7 = fmaxf(a7 / den + bB.w, 0.f);
        uint4 u;
        u.x = (unsigned int)f2bf(o0) | ((unsigned int)f2bf(o1) << 16);
        u.y = (unsigned int)f2bf(o2) | ((unsigned int)f2bf(o3) << 16);
        u.z = (unsigned int)f2bf(o4) | ((unsigned int)f2bf(o5) << 16);
        u.w = (unsigned int)f2bf(o6) | ((unsigned int)f2bf(o7) << 16);
        OUT1b4[(size_t)v * 16 + l] = u;
    }
}

// ---------- GEMM2 via MFMA + fused att2 logits ----------
__global__ __launch_bounds__(256) void gemm2_k(const unsigned int* __restrict__ OUT1b,
                                               const float* __restrict__ W2,
                                               const float* __restrict__ as2,
                                               const float* __restrict__ ad2,
                                               unsigned int* __restrict__ H2b,
                                               float* __restrict__ ALS2,
                                               float* __restrict__ ALD2) {
    __shared__ uint4 Wl[768];   // 12 KiB: 3 ct x 4 kc x 64 lanes
    __shared__ float sas[48], sad[48];
    int t = threadIdx.x;
    if (t < 48) {
        sas[t] = (t < CLS) ? as2[t] : 0.f;
        sad[t] = (t < CLS) ? ad2[t] : 0.f;
    }
    for (int g = t; g < 768; g += 256) {
        int ct = g >> 8, rem = g & 255, kc = rem >> 6, l = rem & 63;
        int c = ct * 16 + (l & 15);
        int k0 = kc * 32 + (l >> 4) * 8;
        U16 u;
#pragma unroll
        for (int j = 0; j < 8; j++)
            u.s[j] = (c < CLS) ? (short)f2bf(W2[(k0 + j) * CLS + c]) : (short)0;
        Wl[g] = u.u;
    }
    __syncthreads();

    int wid = t >> 6, lane = t & 63, quad = lane >> 4, lrow = lane & 15;
    int wrow0 = blockIdx.x * 128 + wid * 32;

    U16 afr[2][4];
#pragma unroll
    for (int rt = 0; rt < 2; rt++) {
        int r = wrow0 + rt * 16 + lrow;
#pragma unroll
        for (int kc = 0; kc < 4; kc++) {
            if (r < NN)
                afr[rt][kc].u = ((const uint4*)OUT1b)[(size_t)r * 16 + kc * 4 + quad];
            else
                afr[rt][kc].u = make_uint4(0, 0, 0, 0);
        }
    }

    float4v acc[2][3];
#pragma unroll
    for (int rt = 0; rt < 2; rt++)
#pragma unroll
        for (int ct = 0; ct < 3; ct++) acc[rt][ct] = (float4v)(0.f);

#pragma unroll
    for (int ct = 0; ct < 3; ct++) {
#pragma unroll
        for (int kc = 0; kc < 4; kc++) {
            U16 b; b.u = Wl[(ct * 4 + kc) * 64 + lane];
            acc[0][ct] = __builtin_amdgcn_mfma_f32_16x16x32_bf16(afr[0][kc].s, b.s, acc[0][ct], 0, 0, 0);
            acc[1][ct] = __builtin_amdgcn_mfma_f32_16x16x32_bf16(afr[1][kc].s, b.s, acc[1][ct], 0, 0, 0);
        }
    }

    // fused att2
#pragma unroll
    for (int rt = 0; rt < 2; rt++) {
#pragma unroll
        for (int reg = 0; reg < 4; reg++) {
            float ps = 0.f, pd = 0.f;
#pragma unroll
            for (int ct = 0; ct < 3; ct++) {
                float v = acc[rt][ct][reg];
                ps += v * sas[ct * 16 + lrow];
                pd += v * sad[ct * 16 + lrow];
            }
#pragma unroll
            for (int o = 1; o < 16; o <<= 1) {
                ps += __shfl_xor(ps, o);
                pd += __shfl_xor(pd, o);
            }
            int r = wrow0 + rt * 16 + quad * 4 + reg;
            if (lrow == 0 && r < NN) {
                ALS2[r] = ps;
                ALD2[r] = pd;
            }
        }
    }

#pragma unroll
    for (int rt = 0; rt < 2; rt++)
#pragma unroll
        for (int ct = 0; ct < 3; ct++)
#pragma unroll
            for (int reg = 0; reg < 4; reg++) {
                float v = acc[rt][ct][reg];
                float o = __shfl_xor(v, 1);
                int r = wrow0 + rt * 16 + quad * 4 + reg;
                int c = ct * 16 + lrow;
                if (((lane & 1) == 0) && c < CLS && r < NN) {
                    unsigned int u = (unsigned int)f2bf(v) | ((unsigned int)f2bf(o) << 16);
                    H2b[(size_t)r * 20 + (c >> 1)] = u;
                }
            }
}

// ---------- gather layer2: 4 nodes/block, 3x20 lanes, 1-ahead pipeline ----------
__global__ __launch_bounds__(256) void gather2_k(const int* __restrict__ cnt,
                                                 const unsigned short* __restrict__ ssrcp,
                                                 const unsigned int* __restrict__ H2b,
                                                 const float* __restrict__ ALS,
                                                 const float* __restrict__ ALD,
                                                 const float* __restrict__ b2,
                                                 float* __restrict__ out) {
    int wid = threadIdx.x >> 6, t = threadIdx.x & 63;
    int v = blockIdx.x * 4 + wid;          // grid*4 == NN exactly
    int deg = min(cnt[v], MAXDEG);
    __shared__ float w[4][MAXDEG];
    __shared__ int sid[4][MAXDEG];
    __shared__ float part[4][3][CLS];
    float den = 0.f;
    float adv = ALD[v];
    if (t < deg) {
        int s = (int)ssrcp[(size_t)v * MAXDEG + t];
        sid[wid][t] = s;
        float l = ALS[s] + adv; l = l > 0.f ? l : NEG * l;
        float e = __expf(l);
        w[wid][t] = e; den = e;
    }
    __syncthreads();
    int g = t / 20, c = t % 20;   // 3 edge-groups x 20 lanes (t<60); c = uint idx (2 ch)
    if (t < 60) {
        float ax = 0.f, ay = 0.f;
        int j = g;
        bool valid = j < deg;
        float wj = 0.f; unsigned int u = 0u;
        if (valid) { wj = w[wid][j]; u = H2b[(size_t)sid[wid][j] * 20 + c]; }
        while (valid) {
            int jn = j + 3;
            bool vn = jn < deg;
            float wn = 0.f; unsigned int un = 0u;
            if (vn) { wn = w[wid][jn]; un = H2b[(size_t)sid[wid][jn] * 20 + c]; }
            ax += wj * bf2f((unsigned short)(u & 0xffffu));
            ay += wj * bf2f((unsigned short)(u >> 16));
            j = jn; valid = vn; wj = wn; u = un;
        }
        part[wid][g][2 * c] = ax;
        part[wid][g][2 * c + 1] = ay;
    }
#pragma unroll
    for (int o = 32; o > 0; o >>= 1) den += __shfl_xor(den, o);
    __syncthreads();
    float z = (t < CLS) ? (part[wid][0][t] + part[wid][1][t] + part[wid][2][t]) / (den + 1e-16f) + b2[t]
                        : -1e30f;
    float mx = z;
#pragma unroll
    for (int o = 32; o > 0; o >>= 1) mx = fmaxf(mx, __shfl_xor(mx, o));
    float ex = (t < CLS) ? __expf(z - mx) : 0.f;
    float se = ex;
#pragma unroll
    for (int o = 32; o > 0; o >>= 1) se += __shfl_xor(se, o);
    if (t < CLS) out[(size_t)v * CLS + t] = z - mx - __logf(se);
}

extern "C" void kernel_launch(void* const* d_in, const int* in_sizes, int n_in,
                              void* d_out, int out_size, void* d_ws, size_t ws_size,
                              hipStream_t stream) {
    const float* x   = (const float*)d_in[0];
    const int*   eix = (const int*)d_in[1];
    const float* W1  = (const float*)d_in[2];
    const float* as1 = (const float*)d_in[3];
    const float* ad1 = (const float*)d_in[4];
    const float* b1  = (const float*)d_in[5];
    const float* W2  = (const float*)d_in[6];
    const float* as2 = (const float*)d_in[7];
    const float* ad2 = (const float*)d_in[8];
    const float* b2  = (const float*)d_in[9];
    float* out = (float*)d_out;

    char* p = (char*)d_ws;
    auto carve = [&](size_t bytes) -> void* {
        void* r = (void*)p;
        p += (bytes + 255) & ~(size_t)255;
        return r;
    };
    unsigned int* H1b   = (unsigned int*)carve((size_t)NN * 64 * 4);   // bf16x2 packed
    unsigned int* OUT1b = (unsigned int*)carve((size_t)NN * 64 * 4);   // bf16x2 packed
    unsigned int* H2b   = (unsigned int*)carve((size_t)NN * 20 * 4);   // bf16x2 packed
    float* ALS1 = (float*)carve((size_t)NN * 4 * 4);
    float* ALD1 = (float*)carve((size_t)NN * 4 * 4);
    float* ALS2 = (float*)carve((size_t)NN * 4);
    float* ALD2 = (float*)carve((size_t)NN * 4);
    int* cnt    = (int*)carve((size_t)NN * 4);
    unsigned short* ssrcp = (unsigned short*)carve((size_t)NN * MAXDEG * 2);
    unsigned int* seg   = (unsigned int*)carve((size_t)P2 * CAP * 4);  // 4 MB pair buffer
    int* seg_cnt        = (int*)carve((size_t)P2 * 4);

    hipMemsetAsync(seg_cnt, 0, (size_t)P2 * 4, stream);

    bucket_k<<<ABLK, 256, 0, stream>>>(eix, seg, seg_cnt);
    bg_k<<<P2 + GEMM1B, 256, 0, stream>>>(seg, seg_cnt, cnt, ssrcp, x, W1, as1, ad1,
                                          H1b, ALS1, ALD1);
    gather1_k<<<NN / 4, 256, 0, stream>>>(cnt, ssrcp, (const uint4*)H1b,
                                          (const float4*)ALS1, (const float4*)ALD1,
                                          b1, (uint4*)OUT1b);
    gemm2_k<<<(NN + 127) / 128, 256, 0, stream>>>(OUT1b, W2, as2, ad2, H2b, ALS2, ALD2);
    gather2_k<<<NN / 4, 256, 0, stream>>>(cnt, ssrcp, H2b, ALS2, ALD2, b2, out);
}